// Round 1
// baseline (982.520 us; speedup 1.0000x reference)
//
#include <hip/hip_runtime.h>

#define NEG_SLOPE 0.2f

__device__ __forceinline__ float lrelu(float x) { return x > 0.0f ? x : NEG_SLOPE * x; }

// wave-uniform broadcast via v_readlane (SGPR result; avoids ds_bpermute)
__device__ __forceinline__ float bcast(float v, int srcLane) {
  return __int_as_float(__builtin_amdgcn_readlane(__float_as_int(v), srcLane));
}

// ---------------------------------------------------------------------------
// K0: fold all small weights.
//  Wz[d][o]   = sum_c W[d][h*32+c] * proj_W[(h*32+c)*32 + j]   (o = h*32+j)
//  Ws[d][h]   = sum_c W[d][h*32+c] * att_src[h][c]
//  Wd[d][h]   = sum_c W[d][h*32+c] * att_dst[h][c]
//  M [d][h]   = sum_c lin_edge_W[d][h*32+c] * att_edge[h][c]
//  cproj[j]   = bias @ proj_W[:,j] + proj_b[j]
// ---------------------------------------------------------------------------
__global__ void k0_setup(const float* __restrict__ W, const float* __restrict__ proj_W,
                         const float* __restrict__ att_src, const float* __restrict__ att_dst,
                         const float* __restrict__ lin_edge_W, const float* __restrict__ att_edge,
                         const float* __restrict__ bias, const float* __restrict__ proj_b,
                         float* __restrict__ Wz, float* __restrict__ Ws, float* __restrict__ Wd,
                         float* __restrict__ M, float* __restrict__ cproj) {
  int t = blockIdx.x * blockDim.x + threadIdx.x;
  if (t < 16384) {
    int d = t >> 7, o = t & 127;
    int h = o >> 5, jj = o & 31;
    float s = 0.f;
    #pragma unroll
    for (int c = 0; c < 32; ++c)
      s += W[d * 128 + h * 32 + c] * proj_W[(h * 32 + c) * 32 + jj];
    Wz[d * 128 + o] = s;
  } else if (t < 16384 + 512) {
    int idx = t - 16384; int d = idx >> 2, h = idx & 3;
    float s = 0.f;
    #pragma unroll
    for (int c = 0; c < 32; ++c) s += W[d * 128 + h * 32 + c] * att_src[h * 32 + c];
    Ws[d * 4 + h] = s;
  } else if (t < 16384 + 1024) {
    int idx = t - 16384 - 512; int d = idx >> 2, h = idx & 3;
    float s = 0.f;
    #pragma unroll
    for (int c = 0; c < 32; ++c) s += W[d * 128 + h * 32 + c] * att_dst[h * 32 + c];
    Wd[d * 4 + h] = s;
  } else if (t < 16384 + 1024 + 128) {
    int idx = t - 16384 - 1024; int d = idx >> 2, h = idx & 3;
    float s = 0.f;
    #pragma unroll
    for (int c = 0; c < 32; ++c) s += lin_edge_W[d * 128 + h * 32 + c] * att_edge[h * 32 + c];
    M[d * 4 + h] = s;
  } else if (t < 16384 + 1024 + 128 + 32) {
    int jj = t - 16384 - 1024 - 128;
    float s = proj_b[jj];
    #pragma unroll
    for (int k = 0; k < 128; ++k) s += bias[k] * proj_W[k * 32 + jj];
    cproj[jj] = s;
  }
}

// ---------------------------------------------------------------------------
// K1: in-degree count
// ---------------------------------------------------------------------------
__global__ void k1_count(const int* __restrict__ dst, int E, int* __restrict__ deg) {
  int i = blockIdx.x * blockDim.x + threadIdx.x;
  if (i < E) atomicAdd(&deg[dst[i]], 1);
}

// ---------------------------------------------------------------------------
// K2: single-block exclusive prefix scan -> offsets[N+1], cursor[N]
// wave-level shfl scans; only ~3 barriers per 1024-chunk.
// ---------------------------------------------------------------------------
__global__ void k2_scan(const int* __restrict__ deg, int n,
                        int* __restrict__ offsets, int* __restrict__ cursor) {
  __shared__ int shw[16];
  __shared__ int shtot;
  int tid = threadIdx.x;
  int lane = tid & 63, wid = tid >> 6;
  int running = 0;
  for (int base = 0; base < n; base += 1024) {
    int i = base + tid;
    int v = (i < n) ? deg[i] : 0;
    int inc = v;
    #pragma unroll
    for (int s = 1; s < 64; s <<= 1) {
      int t = __shfl_up(inc, s);
      if (lane >= s) inc += t;
    }
    if (lane == 63) shw[wid] = inc;
    __syncthreads();
    if (wid == 0) {
      int w = (lane < 16) ? shw[lane] : 0;
      int winc = w;
      #pragma unroll
      for (int s = 1; s < 16; s <<= 1) {
        int t = __shfl_up(winc, s);
        if (lane >= s) winc += t;
      }
      if (lane < 16) shw[lane] = winc - w;  // exclusive wave base
      if (lane == 15) shtot = winc;
    }
    __syncthreads();
    int excl_w = shw[wid];
    if (i < n) {
      int incl = excl_w + inc;
      offsets[i + 1] = running + incl;
      cursor[i] = running + incl - v;
    }
    running += shtot;
    __syncthreads();
  }
  if (tid == 0) offsets[0] = 0;
}

// ---------------------------------------------------------------------------
// K3: [Z | a_src | a_dst] = x @ [Wz | Ws | Wd]
// One wave handles 4 nodes; Wz in LDS as interleaved float2 (64 KB);
// x-row broadcast via readlane (scalar operand into v_fma).
// ---------------------------------------------------------------------------
__global__ __launch_bounds__(256) void k3_gemm(
    const float* __restrict__ x, const float* __restrict__ Wz,
    const float* __restrict__ Ws, const float* __restrict__ Wd,
    int n, float* __restrict__ Z, float* __restrict__ a_src, float* __restrict__ a_dst) {
  __shared__ float2 Wl[128 * 64];  // 64 KB: Wl[k*64+l] = (Wz[k][l], Wz[k][l+64])
  int tid = threadIdx.x;
  for (int idx = tid; idx < 128 * 64; idx += 256) {
    int k = idx >> 6, l = idx & 63;
    Wl[idx] = make_float2(Wz[k * 128 + l], Wz[k * 128 + 64 + l]);
  }
  __syncthreads();
  int lane = tid & 63, wid = tid >> 6;
  float ws0[4], ws1[4], wd0[4], wd1[4];
  #pragma unroll
  for (int h = 0; h < 4; ++h) {
    ws0[h] = Ws[lane * 4 + h];  ws1[h] = Ws[(64 + lane) * 4 + h];
    wd0[h] = Wd[lane * 4 + h];  wd1[h] = Wd[(64 + lane) * 4 + h];
  }
  int gw = blockIdx.x * 4 + wid;
  int nw = gridDim.x * 4;
  for (int base = gw * 4; base < n; base += nw * 4) {
    float xa[4], xb[4];
    #pragma unroll
    for (int u = 0; u < 4; ++u) {
      int node = base + u;
      xa[u] = (node < n) ? x[node * 128 + lane] : 0.0f;
      xb[u] = (node < n) ? x[node * 128 + 64 + lane] : 0.0f;
    }
    float acc0[4] = {0.f, 0.f, 0.f, 0.f}, acc1[4] = {0.f, 0.f, 0.f, 0.f};
    #pragma unroll 16
    for (int k = 0; k < 64; ++k) {
      float2 w = Wl[k * 64 + lane];
      #pragma unroll
      for (int u = 0; u < 4; ++u) {
        float xv = bcast(xa[u], k);
        acc0[u] += xv * w.x; acc1[u] += xv * w.y;
      }
    }
    #pragma unroll 16
    for (int k = 0; k < 64; ++k) {
      float2 w = Wl[(64 + k) * 64 + lane];
      #pragma unroll
      for (int u = 0; u < 4; ++u) {
        float xv = bcast(xb[u], k);
        acc0[u] += xv * w.x; acc1[u] += xv * w.y;
      }
    }
    #pragma unroll
    for (int u = 0; u < 4; ++u) {
      int node = base + u;
      if (node >= n) break;
      Z[node * 128 + lane] = acc0[u];
      Z[node * 128 + 64 + lane] = acc1[u];
      float ps[4], pd[4];
      #pragma unroll
      for (int h = 0; h < 4; ++h) {
        ps[h] = xa[u] * ws0[h] + xb[u] * ws1[h];
        pd[h] = xa[u] * wd0[h] + xb[u] * wd1[h];
      }
      #pragma unroll
      for (int m = 1; m < 64; m <<= 1) {
        #pragma unroll
        for (int h = 0; h < 4; ++h) {
          ps[h] += __shfl_xor(ps[h], m);
          pd[h] += __shfl_xor(pd[h], m);
        }
      }
      if (lane == 0) {
        *(float4*)&a_src[node * 4] = make_float4(ps[0], ps[1], ps[2], ps[3]);
        *(float4*)&a_dst[node * 4] = make_float4(pd[0], pd[1], pd[2], pd[3]);
      }
    }
  }
}

// ---------------------------------------------------------------------------
// K4: per-edge logits + CSR scatter. alpha_raw = leaky(a_src[s]+a_dst[d]+ea@M)
// ---------------------------------------------------------------------------
__global__ __launch_bounds__(256) void k4_edge(
    const int* __restrict__ ei, int E,
    const float* __restrict__ ea, const float* __restrict__ Mg,
    const float* __restrict__ a_src, const float* __restrict__ a_dst,
    float* __restrict__ aeSum, int* __restrict__ cursor,
    int* __restrict__ csr_src, float4* __restrict__ csr_alpha) {
  __shared__ float4 Msh[32];
  if (threadIdx.x < 32) Msh[threadIdx.x] = ((const float4*)Mg)[threadIdx.x];
  __syncthreads();
  int i = blockIdx.x * blockDim.x + threadIdx.x;
  if (i >= E) return;
  const float4* ea4 = (const float4*)ea;
  int s = ei[i], d = ei[E + i];
  float ae0 = 0.f, ae1 = 0.f, ae2 = 0.f, ae3 = 0.f;
  #pragma unroll
  for (int j = 0; j < 8; ++j) {
    float4 v = ea4[i * 8 + j];
    float4 m0 = Msh[j * 4 + 0], m1 = Msh[j * 4 + 1], m2 = Msh[j * 4 + 2], m3 = Msh[j * 4 + 3];
    ae0 += v.x * m0.x + v.y * m1.x + v.z * m2.x + v.w * m3.x;
    ae1 += v.x * m0.y + v.y * m1.y + v.z * m2.y + v.w * m3.y;
    ae2 += v.x * m0.z + v.y * m1.z + v.z * m2.z + v.w * m3.z;
    ae3 += v.x * m0.w + v.y * m1.w + v.z * m2.w + v.w * m3.w;
  }
  float4 as = *(const float4*)&a_src[s * 4];
  float4 ad = *(const float4*)&a_dst[d * 4];
  float al0 = lrelu(as.x + ad.x + ae0);
  float al1 = lrelu(as.y + ad.y + ae1);
  float al2 = lrelu(as.z + ad.z + ae2);
  float al3 = lrelu(as.w + ad.w + ae3);
  atomicAdd(&aeSum[d * 4 + 0], ae0);
  atomicAdd(&aeSum[d * 4 + 1], ae1);
  atomicAdd(&aeSum[d * 4 + 2], ae2);
  atomicAdd(&aeSum[d * 4 + 3], ae3);
  int slot = atomicAdd(&cursor[d], 1);
  csr_src[slot] = s;
  csr_alpha[slot] = make_float4(al0, al1, al2, al3);
}

// ---------------------------------------------------------------------------
// K5: wave-per-node CSR aggregation over Z + fused projection epilogue.
// lane l handles output cols l (h0=l>>5) and l+64 (h0+2); denom replicated
// per 32-lane group. final[j] = sum_h inv[h]*aggZ[h][j]  ->  2 FMA + xor32.
// ---------------------------------------------------------------------------
__global__ __launch_bounds__(256) void k5_agg(
    const int* __restrict__ offsets, const int* __restrict__ csr_src,
    const float* __restrict__ csr_alpha, const float* __restrict__ Z,
    const float* __restrict__ a_src, const float* __restrict__ a_dst,
    const float* __restrict__ aeSum, const float* __restrict__ cproj,
    int n, float* __restrict__ out) {
  int tid = threadIdx.x;
  int lane = tid & 63, wid = tid >> 6;
  int gw = blockIdx.x * 4 + wid, nw = gridDim.x * 4;
  int h0 = lane >> 5, j = lane & 31;
  float cp = cproj[j];
  for (int node = gw; node < n; node += nw) {
    int off0 = offsets[node], off1 = offsets[node + 1];
    int dg = off1 - off0;
    float degf = (float)(dg > 0 ? dg : 1);
    // self-loop term (attr = mean of incoming attrs -> aeSum/deg by linearity)
    float a0 = a_src[node * 4 + h0] + a_dst[node * 4 + h0] + aeSum[node * 4 + h0] / degf;
    float a1 = a_src[node * 4 + 2 + h0] + a_dst[node * 4 + 2 + h0] + aeSum[node * 4 + 2 + h0] / degf;
    float p0 = __expf(lrelu(a0));
    float p1 = __expf(lrelu(a1));
    float dsum0 = p0, dsum1 = p1;
    float agg0 = p0 * Z[node * 128 + lane];
    float agg1 = p1 * Z[node * 128 + 64 + lane];
    for (int i = off0; i < off1; ++i) {
      int s = csr_src[i];
      float q0 = __expf(csr_alpha[i * 4 + h0]);
      float q1 = __expf(csr_alpha[i * 4 + 2 + h0]);
      dsum0 += q0; dsum1 += q1;
      agg0 += q0 * Z[s * 128 + lane];
      agg1 += q1 * Z[s * 128 + 64 + lane];
    }
    float t = agg0 / (dsum0 + 1e-16f) + agg1 / (dsum1 + 1e-16f);
    t += __shfl_xor(t, 32);
    if (lane < 32) out[node * 32 + j] = t + cp;
  }
}

// ---------------------------------------------------------------------------
extern "C" void kernel_launch(void* const* d_in, const int* in_sizes, int n_in,
                              void* d_out, int out_size, void* d_ws, size_t ws_size,
                              hipStream_t stream) {
  const float* x          = (const float*)d_in[0];
  const int*   ei         = (const int*)  d_in[1];
  const float* ea         = (const float*)d_in[2];
  const float* W          = (const float*)d_in[3];
  const float* att_src    = (const float*)d_in[4];
  const float* att_dst    = (const float*)d_in[5];
  const float* lin_edge_W = (const float*)d_in[6];
  const float* att_edge   = (const float*)d_in[7];
  const float* bias       = (const float*)d_in[8];
  const float* proj_W     = (const float*)d_in[9];
  const float* proj_b     = (const float*)d_in[10];
  float* out = (float*)d_out;
  int N = in_sizes[0] / 128;
  int E = in_sizes[1] / 2;

  char* p = (char*)d_ws;
  auto alloc = [&](size_t bytes) {
    char* r = p;
    p += (bytes + 255) & ~(size_t)255;
    return r;
  };
  float* Z         = (float*)alloc((size_t)N * 128 * 4);
  float* a_src     = (float*)alloc((size_t)N * 4 * 4);
  float* a_dst     = (float*)alloc((size_t)N * 4 * 4);
  float* aeSum     = (float*)alloc((size_t)N * 4 * 4);
  int*   deg       = (int*)  alloc((size_t)N * 4);
  int*   offsets   = (int*)  alloc((size_t)(N + 1) * 4);
  int*   cursor    = (int*)  alloc((size_t)N * 4);
  int*   csr_src   = (int*)  alloc((size_t)E * 4);
  float* csr_alpha = (float*)alloc((size_t)E * 16);
  float* Wz        = (float*)alloc(128 * 128 * 4);
  float* Ws        = (float*)alloc(128 * 4 * 4);
  float* Wd        = (float*)alloc(128 * 4 * 4);
  float* M         = (float*)alloc(32 * 4 * 4);
  float* cproj     = (float*)alloc(32 * 4);

  hipMemsetAsync(deg, 0, (size_t)N * 4, stream);
  hipMemsetAsync(aeSum, 0, (size_t)N * 16, stream);

  k0_setup<<<69, 256, 0, stream>>>(W, proj_W, att_src, att_dst, lin_edge_W, att_edge,
                                   bias, proj_b, Wz, Ws, Wd, M, cproj);
  k1_count<<<(E + 255) / 256, 256, 0, stream>>>(ei + E, E, deg);
  k2_scan<<<1, 1024, 0, stream>>>(deg, N, offsets, cursor);
  k3_gemm<<<512, 256, 0, stream>>>(x, Wz, Ws, Wd, N, Z, a_src, a_dst);
  k4_edge<<<(E + 255) / 256, 256, 0, stream>>>(ei, E, ea, M, a_src, a_dst, aeSum,
                                               cursor, csr_src, (float4*)csr_alpha);
  k5_agg<<<2048, 256, 0, stream>>>(offsets, csr_src, csr_alpha, Z, a_src, a_dst,
                                   aeSum, cproj, N, out);
}

// Round 2
// 689.817 us; speedup vs baseline: 1.4243x; 1.4243x over previous
//
#include <hip/hip_runtime.h>

#define NEG_SLOPE 0.2f

__device__ __forceinline__ float lrelu(float x) { return x > 0.0f ? x : NEG_SLOPE * x; }

__device__ __forceinline__ float bcast(float v, int srcLane) {
  return __int_as_float(__builtin_amdgcn_readlane(__float_as_int(v), srcLane));
}

// pack two floats as bf16 (RNE) into one uint: low16 = a, high16 = b
__device__ __forceinline__ unsigned pack_bf16(float a, float b) {
  unsigned ua = __float_as_uint(a), ub = __float_as_uint(b);
  ua += 0x7fffu + ((ua >> 16) & 1u);
  ub += 0x7fffu + ((ub >> 16) & 1u);
  return (ua >> 16) | (ub & 0xffff0000u);
}
__device__ __forceinline__ float bf16lo(unsigned z) { return __uint_as_float(z << 16); }
__device__ __forceinline__ float bf16hi(unsigned z) { return __uint_as_float(z & 0xffff0000u); }

// ---------------------------------------------------------------------------
// K0: fold all small weights.
// ---------------------------------------------------------------------------
__global__ void k0_setup(const float* __restrict__ W, const float* __restrict__ proj_W,
                         const float* __restrict__ att_src, const float* __restrict__ att_dst,
                         const float* __restrict__ lin_edge_W, const float* __restrict__ att_edge,
                         const float* __restrict__ bias, const float* __restrict__ proj_b,
                         float* __restrict__ Wz, float* __restrict__ Ws, float* __restrict__ Wd,
                         float* __restrict__ M, float* __restrict__ cproj) {
  int t = blockIdx.x * blockDim.x + threadIdx.x;
  if (t < 16384) {
    int d = t >> 7, o = t & 127;
    int h = o >> 5, jj = o & 31;
    float s = 0.f;
    #pragma unroll
    for (int c = 0; c < 32; ++c)
      s += W[d * 128 + h * 32 + c] * proj_W[(h * 32 + c) * 32 + jj];
    Wz[d * 128 + o] = s;
  } else if (t < 16384 + 512) {
    int idx = t - 16384; int d = idx >> 2, h = idx & 3;
    float s = 0.f;
    #pragma unroll
    for (int c = 0; c < 32; ++c) s += W[d * 128 + h * 32 + c] * att_src[h * 32 + c];
    Ws[d * 4 + h] = s;
  } else if (t < 16384 + 1024) {
    int idx = t - 16384 - 512; int d = idx >> 2, h = idx & 3;
    float s = 0.f;
    #pragma unroll
    for (int c = 0; c < 32; ++c) s += W[d * 128 + h * 32 + c] * att_dst[h * 32 + c];
    Wd[d * 4 + h] = s;
  } else if (t < 16384 + 1024 + 128) {
    int idx = t - 16384 - 1024; int d = idx >> 2, h = idx & 3;
    float s = 0.f;
    #pragma unroll
    for (int c = 0; c < 32; ++c) s += lin_edge_W[d * 128 + h * 32 + c] * att_edge[h * 32 + c];
    M[d * 4 + h] = s;
  } else if (t < 16384 + 1024 + 128 + 32) {
    int jj = t - 16384 - 1024 - 128;
    float s = proj_b[jj];
    #pragma unroll
    for (int k = 0; k < 128; ++k) s += bias[k] * proj_W[k * 32 + jj];
    cproj[jj] = s;
  }
}

// ---------------------------------------------------------------------------
// K1: in-degree count + per-edge rank (old count value) for CSR slot assignment
// ---------------------------------------------------------------------------
__global__ void k1_count(const int* __restrict__ dst, int E, int* __restrict__ deg,
                         int* __restrict__ rank) {
  int i = blockIdx.x * blockDim.x + threadIdx.x;
  if (i < E) rank[i] = atomicAdd(&deg[dst[i]], 1);
}

// ---------------------------------------------------------------------------
// K2: single-block exclusive prefix scan -> offsets[N+1]; int4 per thread
// ---------------------------------------------------------------------------
__global__ void k2_scan(const int* __restrict__ deg, int n, int* __restrict__ offsets) {
  __shared__ int shw[16];
  __shared__ int shtot;
  int tid = threadIdx.x;
  int lane = tid & 63, wid = tid >> 6;
  int running = 0;
  for (int base = 0; base < n; base += 4096) {
    int i = base + tid * 4;
    int4 v = make_int4(0, 0, 0, 0);
    if (i + 3 < n) v = *(const int4*)&deg[i];
    else {
      if (i < n) v.x = deg[i];
      if (i + 1 < n) v.y = deg[i + 1];
      if (i + 2 < n) v.z = deg[i + 2];
      if (i + 3 < n) v.w = deg[i + 3];
    }
    int tsum = v.x + v.y + v.z + v.w;
    int inc = tsum;
    #pragma unroll
    for (int s = 1; s < 64; s <<= 1) {
      int t = __shfl_up(inc, s);
      if (lane >= s) inc += t;
    }
    if (lane == 63) shw[wid] = inc;
    __syncthreads();
    if (wid == 0) {
      int w = (lane < 16) ? shw[lane] : 0;
      int winc = w;
      #pragma unroll
      for (int s = 1; s < 16; s <<= 1) {
        int t = __shfl_up(winc, s);
        if (lane >= s) winc += t;
      }
      if (lane < 16) shw[lane] = winc - w;
      if (lane == 15) shtot = winc;
    }
    __syncthreads();
    int excl = running + shw[wid] + inc - tsum;  // exclusive prefix for this thread's 4
    if (i < n)     offsets[i + 1] = excl + v.x;
    if (i + 1 < n) offsets[i + 2] = excl + v.x + v.y;
    if (i + 2 < n) offsets[i + 3] = excl + v.x + v.y + v.z;
    if (i + 3 < n) offsets[i + 4] = excl + tsum;
    running += shtot;
    __syncthreads();
  }
  if (tid == 0) offsets[0] = 0;
}

// ---------------------------------------------------------------------------
// K3: Zp (bf16-packed x@Wz) | a_src | a_dst
// ---------------------------------------------------------------------------
__global__ __launch_bounds__(256) void k3_gemm(
    const float* __restrict__ x, const float* __restrict__ Wz,
    const float* __restrict__ Ws, const float* __restrict__ Wd,
    int n, unsigned* __restrict__ Zp, float* __restrict__ a_src, float* __restrict__ a_dst) {
  __shared__ float2 Wl[128 * 64];  // 64 KB: Wl[k*64+l] = (Wz[k][l], Wz[k][l+64])
  int tid = threadIdx.x;
  for (int idx = tid; idx < 128 * 64; idx += 256) {
    int k = idx >> 6, l = idx & 63;
    Wl[idx] = make_float2(Wz[k * 128 + l], Wz[k * 128 + 64 + l]);
  }
  __syncthreads();
  int lane = tid & 63, wid = tid >> 6;
  float ws0[4], ws1[4], wd0[4], wd1[4];
  #pragma unroll
  for (int h = 0; h < 4; ++h) {
    ws0[h] = Ws[lane * 4 + h];  ws1[h] = Ws[(64 + lane) * 4 + h];
    wd0[h] = Wd[lane * 4 + h];  wd1[h] = Wd[(64 + lane) * 4 + h];
  }
  int gw = blockIdx.x * 4 + wid;
  int nw = gridDim.x * 4;
  for (int base = gw * 4; base < n; base += nw * 4) {
    float xa[4], xb[4];
    #pragma unroll
    for (int u = 0; u < 4; ++u) {
      int node = base + u;
      xa[u] = (node < n) ? x[node * 128 + lane] : 0.0f;
      xb[u] = (node < n) ? x[node * 128 + 64 + lane] : 0.0f;
    }
    float acc0[4] = {0.f, 0.f, 0.f, 0.f}, acc1[4] = {0.f, 0.f, 0.f, 0.f};
    #pragma unroll 16
    for (int k = 0; k < 64; ++k) {
      float2 w = Wl[k * 64 + lane];
      #pragma unroll
      for (int u = 0; u < 4; ++u) {
        float xv = bcast(xa[u], k);
        acc0[u] += xv * w.x; acc1[u] += xv * w.y;
      }
    }
    #pragma unroll 16
    for (int k = 0; k < 64; ++k) {
      float2 w = Wl[(64 + k) * 64 + lane];
      #pragma unroll
      for (int u = 0; u < 4; ++u) {
        float xv = bcast(xb[u], k);
        acc0[u] += xv * w.x; acc1[u] += xv * w.y;
      }
    }
    #pragma unroll
    for (int u = 0; u < 4; ++u) {
      int node = base + u;
      if (node >= n) break;
      Zp[(size_t)node * 64 + lane] = pack_bf16(acc0[u], acc1[u]);
      float ps[4], pd[4];
      #pragma unroll
      for (int h = 0; h < 4; ++h) {
        ps[h] = xa[u] * ws0[h] + xb[u] * ws1[h];
        pd[h] = xa[u] * wd0[h] + xb[u] * wd1[h];
      }
      #pragma unroll
      for (int m = 1; m < 64; m <<= 1) {
        #pragma unroll
        for (int h = 0; h < 4; ++h) {
          ps[h] += __shfl_xor(ps[h], m);
          pd[h] += __shfl_xor(pd[h], m);
        }
      }
      if (lane == 0) {
        *(float4*)&a_src[node * 4] = make_float4(ps[0], ps[1], ps[2], ps[3]);
        *(float4*)&a_dst[node * 4] = make_float4(pd[0], pd[1], pd[2], pd[3]);
      }
    }
  }
}

// ---------------------------------------------------------------------------
// K4: per-edge ae = ea@M via LDS-staged coalesced loads; CSR scatter of
// (src, ae[4]). No atomics, no node-table gathers.
// ---------------------------------------------------------------------------
__global__ __launch_bounds__(256) void k4_edge(
    const int* __restrict__ ei, int E, const float4* __restrict__ ea4,
    const float* __restrict__ Mg, const int* __restrict__ rank,
    const int* __restrict__ offsets,
    int* __restrict__ csr_src, float4* __restrict__ csr_ae) {
  __shared__ float4 s_ea4[256 * 9];  // 9 float4 per edge (8 data + 1 pad) = 36 KB
  __shared__ float4 Msh[32];
  int t = threadIdx.x;
  if (t < 32) Msh[t] = ((const float4*)Mg)[t];
  int B0 = blockIdx.x * 256;
  #pragma unroll
  for (int k = 0; k < 8; ++k) {
    int f = k * 256 + t;                    // staged float4 index within block
    int e = B0 + (f >> 3);
    float4 v = (e < E) ? ea4[(size_t)B0 * 8 + f] : make_float4(0.f, 0.f, 0.f, 0.f);
    s_ea4[(f >> 3) * 9 + (f & 7)] = v;
  }
  __syncthreads();
  int e = B0 + t;
  if (e >= E) return;
  float ae0 = 0.f, ae1 = 0.f, ae2 = 0.f, ae3 = 0.f;
  #pragma unroll
  for (int j = 0; j < 8; ++j) {
    float4 v = s_ea4[t * 9 + j];
    float4 m0 = Msh[j * 4 + 0], m1 = Msh[j * 4 + 1], m2 = Msh[j * 4 + 2], m3 = Msh[j * 4 + 3];
    ae0 += v.x * m0.x + v.y * m1.x + v.z * m2.x + v.w * m3.x;
    ae1 += v.x * m0.y + v.y * m1.y + v.z * m2.y + v.w * m3.y;
    ae2 += v.x * m0.z + v.y * m1.z + v.z * m2.z + v.w * m3.z;
    ae3 += v.x * m0.w + v.y * m1.w + v.z * m2.w + v.w * m3.w;
  }
  int s = ei[e], d = ei[E + e];
  int slot = offsets[d] + rank[e];
  csr_src[slot] = s;
  csr_ae[slot] = make_float4(ae0, ae1, ae2, ae3);
}

// ---------------------------------------------------------------------------
// K5: wave-per-node. Pass1 sums ae (self-loop = mean-attr by linearity);
// pass2 reconstructs logits (ae + a_src[s] + a_dst[d]), exp, aggregates
// bf16-packed Z rows, fused projection epilogue.
// ---------------------------------------------------------------------------
__global__ __launch_bounds__(256) void k5_agg(
    const int* __restrict__ offsets, const int* __restrict__ csr_src,
    const float4* __restrict__ csr_ae, const unsigned* __restrict__ Zp,
    const float* __restrict__ a_src, const float* __restrict__ a_dst,
    const float* __restrict__ cproj, int n, float* __restrict__ out) {
  int tid = threadIdx.x;
  int lane = tid & 63, wid = tid >> 6;
  int gw = blockIdx.x * 4 + wid, nw = gridDim.x * 4;
  int h0 = lane >> 5, j = lane & 31;
  float cp = cproj[j];
  for (int node = gw; node < n; node += nw) {
    int off0 = offsets[node], off1 = offsets[node + 1];
    int dg = off1 - off0;
    float inv_deg = 1.0f / (float)(dg > 0 ? dg : 1);
    float ad0 = a_dst[node * 4 + h0], ad1 = a_dst[node * 4 + 2 + h0];
    float asn0 = a_src[node * 4 + h0], asn1 = a_src[node * 4 + 2 + h0];
    // pass 1: sum ae over incoming edges
    float sum0 = 0.f, sum1 = 0.f;
    for (int i = off0; i < off1; ++i) {
      const float* aep = (const float*)(csr_ae + i);
      sum0 += aep[h0]; sum1 += aep[2 + h0];
    }
    // self-loop
    float q0 = __expf(lrelu(asn0 + ad0 + sum0 * inv_deg));
    float q1 = __expf(lrelu(asn1 + ad1 + sum1 * inv_deg));
    float dsum0 = q0, dsum1 = q1;
    unsigned zpn = Zp[(size_t)node * 64 + lane];
    float agg0 = q0 * bf16lo(zpn), agg1 = q1 * bf16hi(zpn);
    // pass 2: unrolled x2 for two independent gather chains
    int i = off0;
    for (; i + 1 < off1; i += 2) {
      int s0 = csr_src[i], s1 = csr_src[i + 1];
      const float* aepa = (const float*)(csr_ae + i);
      const float* aepb = (const float*)(csr_ae + i + 1);
      unsigned zpa = Zp[(size_t)s0 * 64 + lane];
      unsigned zpb = Zp[(size_t)s1 * 64 + lane];
      const float* aspa = &a_src[s0 * 4];
      const float* aspb = &a_src[s1 * 4];
      float ea0 = __expf(lrelu(aepa[h0] + aspa[h0] + ad0));
      float ea1 = __expf(lrelu(aepa[2 + h0] + aspa[2 + h0] + ad1));
      float eb0 = __expf(lrelu(aepb[h0] + aspb[h0] + ad0));
      float eb1 = __expf(lrelu(aepb[2 + h0] + aspb[2 + h0] + ad1));
      dsum0 += ea0 + eb0; dsum1 += ea1 + eb1;
      agg0 += ea0 * bf16lo(zpa) + eb0 * bf16lo(zpb);
      agg1 += ea1 * bf16hi(zpa) + eb1 * bf16hi(zpb);
    }
    if (i < off1) {
      int s0 = csr_src[i];
      const float* aepa = (const float*)(csr_ae + i);
      unsigned zpa = Zp[(size_t)s0 * 64 + lane];
      const float* aspa = &a_src[s0 * 4];
      float ea0 = __expf(lrelu(aepa[h0] + aspa[h0] + ad0));
      float ea1 = __expf(lrelu(aepa[2 + h0] + aspa[2 + h0] + ad1));
      dsum0 += ea0; dsum1 += ea1;
      agg0 += ea0 * bf16lo(zpa);
      agg1 += ea1 * bf16hi(zpa);
    }
    float tt = agg0 / (dsum0 + 1e-16f) + agg1 / (dsum1 + 1e-16f);
    tt += __shfl_xor(tt, 32);
    if (lane < 32) out[node * 32 + j] = tt + cp;
  }
}

// ---------------------------------------------------------------------------
extern "C" void kernel_launch(void* const* d_in, const int* in_sizes, int n_in,
                              void* d_out, int out_size, void* d_ws, size_t ws_size,
                              hipStream_t stream) {
  const float* x          = (const float*)d_in[0];
  const int*   ei         = (const int*)  d_in[1];
  const float* ea         = (const float*)d_in[2];
  const float* W          = (const float*)d_in[3];
  const float* att_src    = (const float*)d_in[4];
  const float* att_dst    = (const float*)d_in[5];
  const float* lin_edge_W = (const float*)d_in[6];
  const float* att_edge   = (const float*)d_in[7];
  const float* bias       = (const float*)d_in[8];
  const float* proj_W     = (const float*)d_in[9];
  const float* proj_b     = (const float*)d_in[10];
  float* out = (float*)d_out;
  int N = in_sizes[0] / 128;
  int E = in_sizes[1] / 2;

  char* p = (char*)d_ws;
  auto alloc = [&](size_t bytes) {
    char* r = p;
    p += (bytes + 255) & ~(size_t)255;
    return r;
  };
  unsigned* Zp     = (unsigned*)alloc((size_t)N * 64 * 4);
  float* a_src     = (float*)alloc((size_t)N * 4 * 4);
  float* a_dst     = (float*)alloc((size_t)N * 4 * 4);
  int*   deg       = (int*)  alloc((size_t)N * 4);
  int*   offsets   = (int*)  alloc((size_t)(N + 1) * 4);
  int*   rank      = (int*)  alloc((size_t)E * 4);
  int*   csr_src   = (int*)  alloc((size_t)E * 4);
  float* csr_ae    = (float*)alloc((size_t)E * 16);
  float* Wz        = (float*)alloc(128 * 128 * 4);
  float* Ws        = (float*)alloc(128 * 4 * 4);
  float* Wd        = (float*)alloc(128 * 4 * 4);
  float* M         = (float*)alloc(32 * 4 * 4);
  float* cproj     = (float*)alloc(32 * 4);

  hipMemsetAsync(deg, 0, (size_t)N * 4, stream);

  k0_setup<<<69, 256, 0, stream>>>(W, proj_W, att_src, att_dst, lin_edge_W, att_edge,
                                   bias, proj_b, Wz, Ws, Wd, M, cproj);
  k1_count<<<(E + 255) / 256, 256, 0, stream>>>(ei + E, E, deg, rank);
  k2_scan<<<1, 1024, 0, stream>>>(deg, N, offsets);
  k3_gemm<<<512, 256, 0, stream>>>(x, Wz, Ws, Wd, N, Zp, a_src, a_dst);
  k4_edge<<<(E + 255) / 256, 256, 0, stream>>>(ei, E, (const float4*)ea, M, rank,
                                               offsets, csr_src, (float4*)csr_ae);
  k5_agg<<<2048, 256, 0, stream>>>(offsets, csr_src, (const float4*)csr_ae, Zp,
                                   a_src, a_dst, cproj, N, out);
}

// Round 3
// 570.850 us; speedup vs baseline: 1.7212x; 1.2084x over previous
//
#include <hip/hip_runtime.h>

#define NEG_SLOPE 0.2f

__device__ __forceinline__ float lrelu(float x) { return x > 0.0f ? x : NEG_SLOPE * x; }

__device__ __forceinline__ float bcast(float v, int srcLane) {
  return __int_as_float(__builtin_amdgcn_readlane(__float_as_int(v), srcLane));
}

// pack two floats as bf16 (RNE) into one uint: low16 = a, high16 = b
__device__ __forceinline__ unsigned pack_bf16(float a, float b) {
  unsigned ua = __float_as_uint(a), ub = __float_as_uint(b);
  ua += 0x7fffu + ((ua >> 16) & 1u);
  ub += 0x7fffu + ((ub >> 16) & 1u);
  return (ua >> 16) | (ub & 0xffff0000u);
}
__device__ __forceinline__ float bf16lo(unsigned z) { return __uint_as_float(z << 16); }
__device__ __forceinline__ float bf16hi(unsigned z) { return __uint_as_float(z & 0xffff0000u); }

// ---------------------------------------------------------------------------
// K0: fold all small weights.
// ---------------------------------------------------------------------------
__global__ void k0_setup(const float* __restrict__ W, const float* __restrict__ proj_W,
                         const float* __restrict__ att_src, const float* __restrict__ att_dst,
                         const float* __restrict__ lin_edge_W, const float* __restrict__ att_edge,
                         const float* __restrict__ bias, const float* __restrict__ proj_b,
                         float* __restrict__ Wz, float* __restrict__ Ws, float* __restrict__ Wd,
                         float* __restrict__ M, float* __restrict__ cproj) {
  int t = blockIdx.x * blockDim.x + threadIdx.x;
  if (t < 16384) {
    int d = t >> 7, o = t & 127;
    int h = o >> 5, jj = o & 31;
    float s = 0.f;
    #pragma unroll
    for (int c = 0; c < 32; ++c)
      s += W[d * 128 + h * 32 + c] * proj_W[(h * 32 + c) * 32 + jj];
    Wz[d * 128 + o] = s;
  } else if (t < 16384 + 512) {
    int idx = t - 16384; int d = idx >> 2, h = idx & 3;
    float s = 0.f;
    #pragma unroll
    for (int c = 0; c < 32; ++c) s += W[d * 128 + h * 32 + c] * att_src[h * 32 + c];
    Ws[d * 4 + h] = s;
  } else if (t < 16384 + 1024) {
    int idx = t - 16384 - 512; int d = idx >> 2, h = idx & 3;
    float s = 0.f;
    #pragma unroll
    for (int c = 0; c < 32; ++c) s += W[d * 128 + h * 32 + c] * att_dst[h * 32 + c];
    Wd[d * 4 + h] = s;
  } else if (t < 16384 + 1024 + 128) {
    int idx = t - 16384 - 1024; int d = idx >> 2, h = idx & 3;
    float s = 0.f;
    #pragma unroll
    for (int c = 0; c < 32; ++c) s += lin_edge_W[d * 128 + h * 32 + c] * att_edge[h * 32 + c];
    M[d * 4 + h] = s;
  } else if (t < 16384 + 1024 + 128 + 32) {
    int jj = t - 16384 - 1024 - 128;
    float s = proj_b[jj];
    #pragma unroll
    for (int k = 0; k < 128; ++k) s += bias[k] * proj_W[k * 32 + jj];
    cproj[jj] = s;
  }
}

// ---------------------------------------------------------------------------
// K1: stream ea -> ae4 (coalesced via LDS staging) + deg/rank atomics.
// The 205 MB stream hides the atomic latency.
// ---------------------------------------------------------------------------
__global__ __launch_bounds__(256) void k1_edge(
    const int* __restrict__ dst, int E, const float4* __restrict__ ea4,
    const float* __restrict__ Mg,
    float4* __restrict__ ae_out, int* __restrict__ deg, int* __restrict__ rank) {
  __shared__ float4 s_ea[256 * 9];  // 9 float4 per edge (8 data + 1 pad) = 36 KB
  __shared__ float4 Msh[32];
  int t = threadIdx.x;
  if (t < 32) Msh[t] = ((const float4*)Mg)[t];
  int B0 = blockIdx.x * 256;
  #pragma unroll
  for (int k = 0; k < 8; ++k) {
    int f = k * 256 + t;
    int e = B0 + (f >> 3);
    float4 v = (e < E) ? ea4[(size_t)B0 * 8 + f] : make_float4(0.f, 0.f, 0.f, 0.f);
    s_ea[(f >> 3) * 9 + (f & 7)] = v;
  }
  __syncthreads();
  int e = B0 + t;
  if (e >= E) return;
  float ae0 = 0.f, ae1 = 0.f, ae2 = 0.f, ae3 = 0.f;
  #pragma unroll
  for (int j = 0; j < 8; ++j) {
    float4 v = s_ea[t * 9 + j];
    float4 m0 = Msh[j * 4 + 0], m1 = Msh[j * 4 + 1], m2 = Msh[j * 4 + 2], m3 = Msh[j * 4 + 3];
    ae0 += v.x * m0.x + v.y * m1.x + v.z * m2.x + v.w * m3.x;
    ae1 += v.x * m0.y + v.y * m1.y + v.z * m2.y + v.w * m3.y;
    ae2 += v.x * m0.z + v.y * m1.z + v.z * m2.z + v.w * m3.z;
    ae3 += v.x * m0.w + v.y * m1.w + v.z * m2.w + v.w * m3.w;
  }
  ae_out[e] = make_float4(ae0, ae1, ae2, ae3);
  rank[e] = atomicAdd(&deg[dst[e]], 1);
}

// ---------------------------------------------------------------------------
// K2: single-block exclusive prefix scan -> offsets[N+1]; int4 per thread
// ---------------------------------------------------------------------------
__global__ void k2_scan(const int* __restrict__ deg, int n, int* __restrict__ offsets) {
  __shared__ int shw[16];
  __shared__ int shtot;
  int tid = threadIdx.x;
  int lane = tid & 63, wid = tid >> 6;
  int running = 0;
  for (int base = 0; base < n; base += 4096) {
    int i = base + tid * 4;
    int4 v = make_int4(0, 0, 0, 0);
    if (i + 3 < n) v = *(const int4*)&deg[i];
    else {
      if (i < n) v.x = deg[i];
      if (i + 1 < n) v.y = deg[i + 1];
      if (i + 2 < n) v.z = deg[i + 2];
      if (i + 3 < n) v.w = deg[i + 3];
    }
    int tsum = v.x + v.y + v.z + v.w;
    int inc = tsum;
    #pragma unroll
    for (int s = 1; s < 64; s <<= 1) {
      int t = __shfl_up(inc, s);
      if (lane >= s) inc += t;
    }
    if (lane == 63) shw[wid] = inc;
    __syncthreads();
    if (wid == 0) {
      int w = (lane < 16) ? shw[lane] : 0;
      int winc = w;
      #pragma unroll
      for (int s = 1; s < 16; s <<= 1) {
        int t = __shfl_up(winc, s);
        if (lane >= s) winc += t;
      }
      if (lane < 16) shw[lane] = winc - w;
      if (lane == 15) shtot = winc;
    }
    __syncthreads();
    int excl = running + shw[wid] + inc - tsum;
    if (i < n)     offsets[i + 1] = excl + v.x;
    if (i + 1 < n) offsets[i + 2] = excl + v.x + v.y;
    if (i + 2 < n) offsets[i + 3] = excl + v.x + v.y + v.z;
    if (i + 3 < n) offsets[i + 4] = excl + tsum;
    running += shtot;
    __syncthreads();
  }
  if (tid == 0) offsets[0] = 0;
}

// ---------------------------------------------------------------------------
// K3: Zp (bf16-packed x@Wz) | a_src | a_dst
// ---------------------------------------------------------------------------
__global__ __launch_bounds__(256) void k3_gemm(
    const float* __restrict__ x, const float* __restrict__ Wz,
    const float* __restrict__ Ws, const float* __restrict__ Wd,
    int n, unsigned* __restrict__ Zp, float* __restrict__ a_src, float* __restrict__ a_dst) {
  __shared__ float2 Wl[128 * 64];  // 64 KB
  int tid = threadIdx.x;
  for (int idx = tid; idx < 128 * 64; idx += 256) {
    int k = idx >> 6, l = idx & 63;
    Wl[idx] = make_float2(Wz[k * 128 + l], Wz[k * 128 + 64 + l]);
  }
  __syncthreads();
  int lane = tid & 63, wid = tid >> 6;
  float ws0[4], ws1[4], wd0[4], wd1[4];
  #pragma unroll
  for (int h = 0; h < 4; ++h) {
    ws0[h] = Ws[lane * 4 + h];  ws1[h] = Ws[(64 + lane) * 4 + h];
    wd0[h] = Wd[lane * 4 + h];  wd1[h] = Wd[(64 + lane) * 4 + h];
  }
  int gw = blockIdx.x * 4 + wid;
  int nw = gridDim.x * 4;
  for (int base = gw * 4; base < n; base += nw * 4) {
    float xa[4], xb[4];
    #pragma unroll
    for (int u = 0; u < 4; ++u) {
      int node = base + u;
      xa[u] = (node < n) ? x[node * 128 + lane] : 0.0f;
      xb[u] = (node < n) ? x[node * 128 + 64 + lane] : 0.0f;
    }
    float acc0[4] = {0.f, 0.f, 0.f, 0.f}, acc1[4] = {0.f, 0.f, 0.f, 0.f};
    #pragma unroll 16
    for (int k = 0; k < 64; ++k) {
      float2 w = Wl[k * 64 + lane];
      #pragma unroll
      for (int u = 0; u < 4; ++u) {
        float xv = bcast(xa[u], k);
        acc0[u] += xv * w.x; acc1[u] += xv * w.y;
      }
    }
    #pragma unroll 16
    for (int k = 0; k < 64; ++k) {
      float2 w = Wl[(64 + k) * 64 + lane];
      #pragma unroll
      for (int u = 0; u < 4; ++u) {
        float xv = bcast(xb[u], k);
        acc0[u] += xv * w.x; acc1[u] += xv * w.y;
      }
    }
    #pragma unroll
    for (int u = 0; u < 4; ++u) {
      int node = base + u;
      if (node >= n) break;
      Zp[(size_t)node * 64 + lane] = pack_bf16(acc0[u], acc1[u]);
      float ps[4], pd[4];
      #pragma unroll
      for (int h = 0; h < 4; ++h) {
        ps[h] = xa[u] * ws0[h] + xb[u] * ws1[h];
        pd[h] = xa[u] * wd0[h] + xb[u] * wd1[h];
      }
      #pragma unroll
      for (int m = 1; m < 64; m <<= 1) {
        #pragma unroll
        for (int h = 0; h < 4; ++h) {
          ps[h] += __shfl_xor(ps[h], m);
          pd[h] += __shfl_xor(pd[h], m);
        }
      }
      if (lane == 0) {
        *(float4*)&a_src[node * 4] = make_float4(ps[0], ps[1], ps[2], ps[3]);
        *(float4*)&a_dst[node * 4] = make_float4(pd[0], pd[1], pd[2], pd[3]);
      }
    }
  }
}

// ---------------------------------------------------------------------------
// K4: tiny 4B permutation scatter: perm[offsets[dst]+rank] = e
// ---------------------------------------------------------------------------
__global__ void k4_perm(const int* __restrict__ dst, int E,
                        const int* __restrict__ rank, const int* __restrict__ offsets,
                        int* __restrict__ perm) {
  int e = blockIdx.x * blockDim.x + threadIdx.x;
  if (e < E) perm[offsets[dst[e]] + rank[e]] = e;
}

// ---------------------------------------------------------------------------
// K5: wave-per-node, two-phase per 64-edge chunk.
// Phase A (lane-per-edge): gather ae4[e], a_src[s]; compute 4 exp-weights
//   once; stash (w permuted as x,z,y,w  +  src) in LDS; accumulate per-lane
//   dsum/aeSum partials.
// Phase B (lane-per-column): coalesced Zp row gather + 2 LDS broadcast
//   reads + 2 FMAs per edge, unrolled x4.
// ---------------------------------------------------------------------------
__global__ __launch_bounds__(256) void k5_agg(
    const int* __restrict__ offsets, const int* __restrict__ perm,
    const int* __restrict__ ei_src, const float4* __restrict__ ae4,
    const unsigned* __restrict__ Zp,
    const float* __restrict__ a_src, const float* __restrict__ a_dst,
    const float* __restrict__ cproj, int n, float* __restrict__ out) {
  __shared__ float4 s_w[4][64];
  __shared__ int    s_s[4][64];
  int tid = threadIdx.x;
  int lane = tid & 63, wid = tid >> 6;
  int gw = blockIdx.x * 4 + wid, nw = gridDim.x * 4;
  int h0 = lane >> 5, j = lane & 31;
  float cp = cproj[j];
  const float* wbase = (const float*)&s_w[wid][0];
  for (int node = gw; node < n; node += nw) {
    int off0 = offsets[node], off1 = offsets[node + 1];
    int dg = off1 - off0;
    float4 ad = *(const float4*)&a_dst[node * 4];
    float dsx = 0.f, dsy = 0.f, dsz = 0.f, dsw = 0.f;
    float aex = 0.f, aey = 0.f, aez = 0.f, aew = 0.f;
    float agg0 = 0.f, agg1 = 0.f;
    for (int base = off0; base < off1; base += 64) {
      int rem = off1 - base; if (rem > 64) rem = 64;
      int i = base + lane;
      // ---- phase A ----
      if (lane < rem) {
        int e = perm[i];
        int s = ei_src[e];
        float4 a = ae4[e];
        float4 as = *(const float4*)&a_src[s * 4];
        float4 w;
        w.x = __expf(lrelu(a.x + as.x + ad.x));
        w.y = __expf(lrelu(a.y + as.y + ad.y));
        w.z = __expf(lrelu(a.z + as.z + ad.z));
        w.w = __expf(lrelu(a.w + as.w + ad.w));
        dsx += w.x; dsy += w.y; dsz += w.z; dsw += w.w;
        aex += a.x; aey += a.y; aez += a.z; aew += a.w;
        s_w[wid][lane] = make_float4(w.x, w.z, w.y, w.w);  // pair (h, h+2) adjacent
        s_s[wid][lane] = s;
      }
      // ---- phase B ----
      int jj = 0;
      for (; jj + 4 <= rem; jj += 4) {
        int s0 = s_s[wid][jj], s1 = s_s[wid][jj + 1];
        int s2 = s_s[wid][jj + 2], s3 = s_s[wid][jj + 3];
        unsigned z0 = Zp[(size_t)s0 * 64 + lane];
        unsigned z1 = Zp[(size_t)s1 * 64 + lane];
        unsigned z2 = Zp[(size_t)s2 * 64 + lane];
        unsigned z3 = Zp[(size_t)s3 * 64 + lane];
        float2 w0 = *(const float2*)(wbase + (jj    ) * 4 + 2 * h0);
        float2 w1 = *(const float2*)(wbase + (jj + 1) * 4 + 2 * h0);
        float2 w2 = *(const float2*)(wbase + (jj + 2) * 4 + 2 * h0);
        float2 w3 = *(const float2*)(wbase + (jj + 3) * 4 + 2 * h0);
        agg0 += w0.x * bf16lo(z0) + w1.x * bf16lo(z1) + w2.x * bf16lo(z2) + w3.x * bf16lo(z3);
        agg1 += w0.y * bf16hi(z0) + w1.y * bf16hi(z1) + w2.y * bf16hi(z2) + w3.y * bf16hi(z3);
      }
      for (; jj < rem; ++jj) {
        int s0 = s_s[wid][jj];
        unsigned z0 = Zp[(size_t)s0 * 64 + lane];
        float2 w0 = *(const float2*)(wbase + jj * 4 + 2 * h0);
        agg0 += w0.x * bf16lo(z0);
        agg1 += w0.y * bf16hi(z0);
      }
    }
    // ---- wave reduction of dsum / aeSum partials ----
    #pragma unroll
    for (int m = 1; m < 64; m <<= 1) {
      dsx += __shfl_xor(dsx, m); dsy += __shfl_xor(dsy, m);
      dsz += __shfl_xor(dsz, m); dsw += __shfl_xor(dsw, m);
      aex += __shfl_xor(aex, m); aey += __shfl_xor(aey, m);
      aez += __shfl_xor(aez, m); aew += __shfl_xor(aew, m);
    }
    // ---- self-loop (attr = mean of incoming -> aeSum/deg by linearity) ----
    float invd = 1.0f / (float)(dg > 0 ? dg : 1);
    float4 asn = *(const float4*)&a_src[node * 4];
    float w0 = __expf(lrelu(asn.x + ad.x + aex * invd));
    float w1 = __expf(lrelu(asn.y + ad.y + aey * invd));
    float w2 = __expf(lrelu(asn.z + ad.z + aez * invd));
    float w3 = __expf(lrelu(asn.w + ad.w + aew * invd));
    dsx += w0; dsy += w1; dsz += w2; dsw += w3;
    unsigned zpn = Zp[(size_t)node * 64 + lane];
    float sw0 = h0 ? w1 : w0, sw1 = h0 ? w3 : w2;
    agg0 += sw0 * bf16lo(zpn);
    agg1 += sw1 * bf16hi(zpn);
    float d0 = h0 ? dsy : dsx, d1 = h0 ? dsw : dsz;
    float tt = agg0 / (d0 + 1e-16f) + agg1 / (d1 + 1e-16f);
    tt += __shfl_xor(tt, 32);
    if (lane < 32) out[node * 32 + j] = tt + cp;
  }
}

// ---------------------------------------------------------------------------
extern "C" void kernel_launch(void* const* d_in, const int* in_sizes, int n_in,
                              void* d_out, int out_size, void* d_ws, size_t ws_size,
                              hipStream_t stream) {
  const float* x          = (const float*)d_in[0];
  const int*   ei         = (const int*)  d_in[1];
  const float* ea         = (const float*)d_in[2];
  const float* W          = (const float*)d_in[3];
  const float* att_src    = (const float*)d_in[4];
  const float* att_dst    = (const float*)d_in[5];
  const float* lin_edge_W = (const float*)d_in[6];
  const float* att_edge   = (const float*)d_in[7];
  const float* bias       = (const float*)d_in[8];
  const float* proj_W     = (const float*)d_in[9];
  const float* proj_b     = (const float*)d_in[10];
  float* out = (float*)d_out;
  int N = in_sizes[0] / 128;
  int E = in_sizes[1] / 2;

  char* p = (char*)d_ws;
  auto alloc = [&](size_t bytes) {
    char* r = p;
    p += (bytes + 255) & ~(size_t)255;
    return r;
  };
  unsigned* Zp     = (unsigned*)alloc((size_t)N * 64 * 4);
  float* a_src     = (float*)alloc((size_t)N * 4 * 4);
  float* a_dst     = (float*)alloc((size_t)N * 4 * 4);
  int*   deg       = (int*)  alloc((size_t)N * 4);
  int*   offsets   = (int*)  alloc((size_t)(N + 1) * 4);
  int*   rank      = (int*)  alloc((size_t)E * 4);
  int*   perm      = (int*)  alloc((size_t)E * 4);
  float* ae_seq    = (float*)alloc((size_t)E * 16);
  float* Wz        = (float*)alloc(128 * 128 * 4);
  float* Ws        = (float*)alloc(128 * 4 * 4);
  float* Wd        = (float*)alloc(128 * 4 * 4);
  float* M         = (float*)alloc(32 * 4 * 4);
  float* cproj     = (float*)alloc(32 * 4);

  hipMemsetAsync(deg, 0, (size_t)N * 4, stream);

  k0_setup<<<69, 256, 0, stream>>>(W, proj_W, att_src, att_dst, lin_edge_W, att_edge,
                                   bias, proj_b, Wz, Ws, Wd, M, cproj);
  k1_edge<<<(E + 255) / 256, 256, 0, stream>>>(ei + E, E, (const float4*)ea, M,
                                               (float4*)ae_seq, deg, rank);
  k2_scan<<<1, 1024, 0, stream>>>(deg, N, offsets);
  k3_gemm<<<512, 256, 0, stream>>>(x, Wz, Ws, Wd, N, Zp, a_src, a_dst);
  k4_perm<<<(E + 255) / 256, 256, 0, stream>>>(ei + E, E, rank, offsets, perm);
  k5_agg<<<2048, 256, 0, stream>>>(offsets, perm, ei, (const float4*)ae_seq, Zp,
                                   a_src, a_dst, cproj, N, out);
}

// Round 4
// 558.243 us; speedup vs baseline: 1.7600x; 1.0226x over previous
//
#include <hip/hip_runtime.h>

#define NEG_SLOPE 0.2f

__device__ __forceinline__ float lrelu(float x) { return x > 0.0f ? x : NEG_SLOPE * x; }

__device__ __forceinline__ float bcast(float v, int srcLane) {
  return __int_as_float(__builtin_amdgcn_readlane(__float_as_int(v), srcLane));
}

// pack two floats as bf16 (RNE) into one uint: low16 = a, high16 = b
__device__ __forceinline__ unsigned pack_bf16(float a, float b) {
  unsigned ua = __float_as_uint(a), ub = __float_as_uint(b);
  ua += 0x7fffu + ((ua >> 16) & 1u);
  ub += 0x7fffu + ((ub >> 16) & 1u);
  return (ua >> 16) | (ub & 0xffff0000u);
}
__device__ __forceinline__ float bf16lo(unsigned z) { return __uint_as_float(z << 16); }
__device__ __forceinline__ float bf16hi(unsigned z) { return __uint_as_float(z & 0xffff0000u); }

// ---------------------------------------------------------------------------
// K0: fold all small weights.
// ---------------------------------------------------------------------------
__global__ void k0_setup(const float* __restrict__ W, const float* __restrict__ proj_W,
                         const float* __restrict__ att_src, const float* __restrict__ att_dst,
                         const float* __restrict__ lin_edge_W, const float* __restrict__ att_edge,
                         const float* __restrict__ bias, const float* __restrict__ proj_b,
                         float* __restrict__ Wz, float* __restrict__ Ws, float* __restrict__ Wd,
                         float* __restrict__ M, float* __restrict__ cproj) {
  int t = blockIdx.x * blockDim.x + threadIdx.x;
  if (t < 16384) {
    int d = t >> 7, o = t & 127;
    int h = o >> 5, jj = o & 31;
    float s = 0.f;
    #pragma unroll
    for (int c = 0; c < 32; ++c)
      s += W[d * 128 + h * 32 + c] * proj_W[(h * 32 + c) * 32 + jj];
    Wz[d * 128 + o] = s;
  } else if (t < 16384 + 512) {
    int idx = t - 16384; int d = idx >> 2, h = idx & 3;
    float s = 0.f;
    #pragma unroll
    for (int c = 0; c < 32; ++c) s += W[d * 128 + h * 32 + c] * att_src[h * 32 + c];
    Ws[d * 4 + h] = s;
  } else if (t < 16384 + 1024) {
    int idx = t - 16384 - 512; int d = idx >> 2, h = idx & 3;
    float s = 0.f;
    #pragma unroll
    for (int c = 0; c < 32; ++c) s += W[d * 128 + h * 32 + c] * att_dst[h * 32 + c];
    Wd[d * 4 + h] = s;
  } else if (t < 16384 + 1024 + 128) {
    int idx = t - 16384 - 1024; int d = idx >> 2, h = idx & 3;
    float s = 0.f;
    #pragma unroll
    for (int c = 0; c < 32; ++c) s += lin_edge_W[d * 128 + h * 32 + c] * att_edge[h * 32 + c];
    M[d * 4 + h] = s;
  } else if (t < 16384 + 1024 + 128 + 32) {
    int jj = t - 16384 - 1024 - 128;
    float s = proj_b[jj];
    #pragma unroll
    for (int k = 0; k < 128; ++k) s += bias[k] * proj_W[k * 32 + jj];
    cproj[jj] = s;
  }
}

// ---------------------------------------------------------------------------
// K3: Zp (bf16-packed x@Wz) | a_src | a_dst   (runs BEFORE the edge pass)
// ---------------------------------------------------------------------------
__global__ __launch_bounds__(256) void k3_gemm(
    const float* __restrict__ x, const float* __restrict__ Wz,
    const float* __restrict__ Ws, const float* __restrict__ Wd,
    int n, unsigned* __restrict__ Zp, float* __restrict__ a_src, float* __restrict__ a_dst) {
  __shared__ float2 Wl[128 * 64];  // 64 KB
  int tid = threadIdx.x;
  for (int idx = tid; idx < 128 * 64; idx += 256) {
    int k = idx >> 6, l = idx & 63;
    Wl[idx] = make_float2(Wz[k * 128 + l], Wz[k * 128 + 64 + l]);
  }
  __syncthreads();
  int lane = tid & 63, wid = tid >> 6;
  float ws0[4], ws1[4], wd0[4], wd1[4];
  #pragma unroll
  for (int h = 0; h < 4; ++h) {
    ws0[h] = Ws[lane * 4 + h];  ws1[h] = Ws[(64 + lane) * 4 + h];
    wd0[h] = Wd[lane * 4 + h];  wd1[h] = Wd[(64 + lane) * 4 + h];
  }
  int gw = blockIdx.x * 4 + wid;
  int nw = gridDim.x * 4;
  for (int base = gw * 4; base < n; base += nw * 4) {
    float xa[4], xb[4];
    #pragma unroll
    for (int u = 0; u < 4; ++u) {
      int node = base + u;
      xa[u] = (node < n) ? x[node * 128 + lane] : 0.0f;
      xb[u] = (node < n) ? x[node * 128 + 64 + lane] : 0.0f;
    }
    float acc0[4] = {0.f, 0.f, 0.f, 0.f}, acc1[4] = {0.f, 0.f, 0.f, 0.f};
    #pragma unroll 16
    for (int k = 0; k < 64; ++k) {
      float2 w = Wl[k * 64 + lane];
      #pragma unroll
      for (int u = 0; u < 4; ++u) {
        float xv = bcast(xa[u], k);
        acc0[u] += xv * w.x; acc1[u] += xv * w.y;
      }
    }
    #pragma unroll 16
    for (int k = 0; k < 64; ++k) {
      float2 w = Wl[(64 + k) * 64 + lane];
      #pragma unroll
      for (int u = 0; u < 4; ++u) {
        float xv = bcast(xb[u], k);
        acc0[u] += xv * w.x; acc1[u] += xv * w.y;
      }
    }
    #pragma unroll
    for (int u = 0; u < 4; ++u) {
      int node = base + u;
      if (node >= n) break;
      Zp[(size_t)node * 64 + lane] = pack_bf16(acc0[u], acc1[u]);
      float ps[4], pd[4];
      #pragma unroll
      for (int h = 0; h < 4; ++h) {
        ps[h] = xa[u] * ws0[h] + xb[u] * ws1[h];
        pd[h] = xa[u] * wd0[h] + xb[u] * wd1[h];
      }
      #pragma unroll
      for (int m = 1; m < 64; m <<= 1) {
        #pragma unroll
        for (int h = 0; h < 4; ++h) {
          ps[h] += __shfl_xor(ps[h], m);
          pd[h] += __shfl_xor(pd[h], m);
        }
      }
      if (lane == 0) {
        *(float4*)&a_src[node * 4] = make_float4(ps[0], ps[1], ps[2], ps[3]);
        *(float4*)&a_dst[node * 4] = make_float4(pd[0], pd[1], pd[2], pd[3]);
      }
    }
  }
}

// ---------------------------------------------------------------------------
// K1: stream ea -> ae; gather a_src[s], a_dst[d]; compute final exp-weights;
// write we[e] = {w01,w23,ae01,ae23} bf16-packed (coalesced); rank atomic.
// ---------------------------------------------------------------------------
__global__ __launch_bounds__(256) void k1_edge(
    const int* __restrict__ ei, int E, const float4* __restrict__ ea4,
    const float* __restrict__ Mg,
    const float* __restrict__ a_src, const float* __restrict__ a_dst,
    uint4* __restrict__ we, int* __restrict__ deg, int* __restrict__ rank) {
  __shared__ float4 s_ea[256 * 9];  // 8 data + 1 pad per edge = 36 KB
  __shared__ float4 Msh[32];
  int t = threadIdx.x;
  if (t < 32) Msh[t] = ((const float4*)Mg)[t];
  int B0 = blockIdx.x * 256;
  #pragma unroll
  for (int k = 0; k < 8; ++k) {
    int f = k * 256 + t;
    int e = B0 + (f >> 3);
    float4 v = (e < E) ? ea4[(size_t)B0 * 8 + f] : make_float4(0.f, 0.f, 0.f, 0.f);
    s_ea[(f >> 3) * 9 + (f & 7)] = v;
  }
  __syncthreads();
  int e = B0 + t;
  if (e >= E) return;
  // start the index + gather chain early
  int s = ei[e], d = ei[E + e];
  float4 as = *(const float4*)&a_src[(size_t)s * 4];
  float4 ad = *(const float4*)&a_dst[(size_t)d * 4];
  float ae0 = 0.f, ae1 = 0.f, ae2 = 0.f, ae3 = 0.f;
  #pragma unroll
  for (int j = 0; j < 8; ++j) {
    float4 v = s_ea[t * 9 + j];
    float4 m0 = Msh[j * 4 + 0], m1 = Msh[j * 4 + 1], m2 = Msh[j * 4 + 2], m3 = Msh[j * 4 + 3];
    ae0 += v.x * m0.x + v.y * m1.x + v.z * m2.x + v.w * m3.x;
    ae1 += v.x * m0.y + v.y * m1.y + v.z * m2.y + v.w * m3.y;
    ae2 += v.x * m0.z + v.y * m1.z + v.z * m2.z + v.w * m3.z;
    ae3 += v.x * m0.w + v.y * m1.w + v.z * m2.w + v.w * m3.w;
  }
  float w0 = __expf(lrelu(ae0 + as.x + ad.x));
  float w1 = __expf(lrelu(ae1 + as.y + ad.y));
  float w2 = __expf(lrelu(ae2 + as.z + ad.z));
  float w3 = __expf(lrelu(ae3 + as.w + ad.w));
  we[e] = make_uint4(pack_bf16(w0, w1), pack_bf16(w2, w3),
                     pack_bf16(ae0, ae1), pack_bf16(ae2, ae3));
  rank[e] = atomicAdd(&deg[d], 1);
}

// ---------------------------------------------------------------------------
// K2: single-block exclusive prefix scan -> offsets[N+1]; int4 per thread
// ---------------------------------------------------------------------------
__global__ void k2_scan(const int* __restrict__ deg, int n, int* __restrict__ offsets) {
  __shared__ int shw[16];
  __shared__ int shtot;
  int tid = threadIdx.x;
  int lane = tid & 63, wid = tid >> 6;
  int running = 0;
  for (int base = 0; base < n; base += 4096) {
    int i = base + tid * 4;
    int4 v = make_int4(0, 0, 0, 0);
    if (i + 3 < n) v = *(const int4*)&deg[i];
    else {
      if (i < n) v.x = deg[i];
      if (i + 1 < n) v.y = deg[i + 1];
      if (i + 2 < n) v.z = deg[i + 2];
      if (i + 3 < n) v.w = deg[i + 3];
    }
    int tsum = v.x + v.y + v.z + v.w;
    int inc = tsum;
    #pragma unroll
    for (int s = 1; s < 64; s <<= 1) {
      int t = __shfl_up(inc, s);
      if (lane >= s) inc += t;
    }
    if (lane == 63) shw[wid] = inc;
    __syncthreads();
    if (wid == 0) {
      int w = (lane < 16) ? shw[lane] : 0;
      int winc = w;
      #pragma unroll
      for (int s = 1; s < 16; s <<= 1) {
        int t = __shfl_up(winc, s);
        if (lane >= s) winc += t;
      }
      if (lane < 16) shw[lane] = winc - w;
      if (lane == 15) shtot = winc;
    }
    __syncthreads();
    int excl = running + shw[wid] + inc - tsum;
    if (i < n)     offsets[i + 1] = excl + v.x;
    if (i + 1 < n) offsets[i + 2] = excl + v.x + v.y;
    if (i + 2 < n) offsets[i + 3] = excl + v.x + v.y + v.z;
    if (i + 3 < n) offsets[i + 4] = excl + tsum;
    running += shtot;
    __syncthreads();
  }
  if (tid == 0) offsets[0] = 0;
}

// ---------------------------------------------------------------------------
// K4: scatter one 32B CSR entry per edge: {src, -, -, -, we.x..we.w}
// (both stores hit the same cache line -> 1 RFO line per edge)
// ---------------------------------------------------------------------------
__global__ void k4_scatter(const int* __restrict__ ei, int E,
                           const int* __restrict__ rank, const int* __restrict__ offsets,
                           const uint4* __restrict__ we, uint4* __restrict__ csr) {
  int e = blockIdx.x * blockDim.x + threadIdx.x;
  if (e >= E) return;
  int s = ei[e], d = ei[E + e];
  int slot = offsets[d] + rank[e];
  uint4 w = we[e];
  uint4* ent = &csr[(size_t)slot * 2];
  *(int*)ent = s;
  ent[1] = w;
}

// ---------------------------------------------------------------------------
// K5: wave-per-node. Phase A: coalesced CSR stream (no gathers, no exp) ->
// dsum/aeSum partials + LDS stash. Phase B: Zp row gather + 2 FMA/edge.
// ---------------------------------------------------------------------------
__global__ __launch_bounds__(256) void k5_agg(
    const int* __restrict__ offsets, const uint4* __restrict__ csr,
    const unsigned* __restrict__ Zp,
    const float* __restrict__ a_src, const float* __restrict__ a_dst,
    const float* __restrict__ cproj, int n, float* __restrict__ out) {
  __shared__ float4 s_w[4][64];
  __shared__ int    s_s[4][64];
  int tid = threadIdx.x;
  int lane = tid & 63, wid = tid >> 6;
  int gw = blockIdx.x * 4 + wid, nw = gridDim.x * 4;
  int h0 = lane >> 5, j = lane & 31;
  float cp = cproj[j];
  const float* wbase = (const float*)&s_w[wid][0];
  for (int node = gw; node < n; node += nw) {
    int off0 = offsets[node], off1 = offsets[node + 1];
    int dg = off1 - off0;
    float dsx = 0.f, dsy = 0.f, dsz = 0.f, dsw = 0.f;
    float aex = 0.f, aey = 0.f, aez = 0.f, aew = 0.f;
    float agg0 = 0.f, agg1 = 0.f;
    for (int base = off0; base < off1; base += 64) {
      int rem = off1 - base; if (rem > 64) rem = 64;
      // ---- phase A: coalesced CSR read ----
      if (lane < rem) {
        const uint4* ent = &csr[(size_t)(base + lane) * 2];
        int s = *(const int*)ent;
        uint4 w = ent[1];
        float w0 = bf16lo(w.x), w1 = bf16hi(w.x);
        float w2 = bf16lo(w.y), w3 = bf16hi(w.y);
        dsx += w0; dsy += w1; dsz += w2; dsw += w3;
        aex += bf16lo(w.z); aey += bf16hi(w.z);
        aez += bf16lo(w.w); aew += bf16hi(w.w);
        s_w[wid][lane] = make_float4(w0, w2, w1, w3);  // pair (h, h+2) adjacent
        s_s[wid][lane] = s;
      }
      // ---- phase B ----
      int jj = 0;
      for (; jj + 4 <= rem; jj += 4) {
        int s0 = s_s[wid][jj], s1 = s_s[wid][jj + 1];
        int s2 = s_s[wid][jj + 2], s3 = s_s[wid][jj + 3];
        unsigned z0 = Zp[(size_t)s0 * 64 + lane];
        unsigned z1 = Zp[(size_t)s1 * 64 + lane];
        unsigned z2 = Zp[(size_t)s2 * 64 + lane];
        unsigned z3 = Zp[(size_t)s3 * 64 + lane];
        float2 w0 = *(const float2*)(wbase + (jj    ) * 4 + 2 * h0);
        float2 w1 = *(const float2*)(wbase + (jj + 1) * 4 + 2 * h0);
        float2 w2 = *(const float2*)(wbase + (jj + 2) * 4 + 2 * h0);
        float2 w3 = *(const float2*)(wbase + (jj + 3) * 4 + 2 * h0);
        agg0 += w0.x * bf16lo(z0) + w1.x * bf16lo(z1) + w2.x * bf16lo(z2) + w3.x * bf16lo(z3);
        agg1 += w0.y * bf16hi(z0) + w1.y * bf16hi(z1) + w2.y * bf16hi(z2) + w3.y * bf16hi(z3);
      }
      for (; jj < rem; ++jj) {
        int s0 = s_s[wid][jj];
        unsigned z0 = Zp[(size_t)s0 * 64 + lane];
        float2 w0 = *(const float2*)(wbase + jj * 4 + 2 * h0);
        agg0 += w0.x * bf16lo(z0);
        agg1 += w0.y * bf16hi(z0);
      }
    }
    // ---- wave reduction of dsum / aeSum partials ----
    #pragma unroll
    for (int m = 1; m < 64; m <<= 1) {
      dsx += __shfl_xor(dsx, m); dsy += __shfl_xor(dsy, m);
      dsz += __shfl_xor(dsz, m); dsw += __shfl_xor(dsw, m);
      aex += __shfl_xor(aex, m); aey += __shfl_xor(aey, m);
      aez += __shfl_xor(aez, m); aew += __shfl_xor(aew, m);
    }
    // ---- self-loop (attr = mean of incoming -> aeSum/deg by linearity) ----
    float invd = 1.0f / (float)(dg > 0 ? dg : 1);
    float4 asn = *(const float4*)&a_src[node * 4];
    float4 ad  = *(const float4*)&a_dst[node * 4];
    float w0 = __expf(lrelu(asn.x + ad.x + aex * invd));
    float w1 = __expf(lrelu(asn.y + ad.y + aey * invd));
    float w2 = __expf(lrelu(asn.z + ad.z + aez * invd));
    float w3 = __expf(lrelu(asn.w + ad.w + aew * invd));
    dsx += w0; dsy += w1; dsz += w2; dsw += w3;
    unsigned zpn = Zp[(size_t)node * 64 + lane];
    float sw0 = h0 ? w1 : w0, sw1 = h0 ? w3 : w2;
    agg0 += sw0 * bf16lo(zpn);
    agg1 += sw1 * bf16hi(zpn);
    float d0 = h0 ? dsy : dsx, d1 = h0 ? dsw : dsz;
    float tt = agg0 / (d0 + 1e-16f) + agg1 / (d1 + 1e-16f);
    tt += __shfl_xor(tt, 32);
    if (lane < 32) out[node * 32 + j] = tt + cp;
  }
}

// ---------------------------------------------------------------------------
extern "C" void kernel_launch(void* const* d_in, const int* in_sizes, int n_in,
                              void* d_out, int out_size, void* d_ws, size_t ws_size,
                              hipStream_t stream) {
  const float* x          = (const float*)d_in[0];
  const int*   ei         = (const int*)  d_in[1];
  const float* ea         = (const float*)d_in[2];
  const float* W          = (const float*)d_in[3];
  const float* att_src    = (const float*)d_in[4];
  const float* att_dst    = (const float*)d_in[5];
  const float* lin_edge_W = (const float*)d_in[6];
  const float* att_edge   = (const float*)d_in[7];
  const float* bias       = (const float*)d_in[8];
  const float* proj_W     = (const float*)d_in[9];
  const float* proj_b     = (const float*)d_in[10];
  float* out = (float*)d_out;
  int N = in_sizes[0] / 128;
  int E = in_sizes[1] / 2;

  char* p = (char*)d_ws;
  auto alloc = [&](size_t bytes) {
    char* r = p;
    p += (bytes + 255) & ~(size_t)255;
    return r;
  };
  unsigned* Zp     = (unsigned*)alloc((size_t)N * 64 * 4);
  float* a_src     = (float*)alloc((size_t)N * 4 * 4);
  float* a_dst     = (float*)alloc((size_t)N * 4 * 4);
  int*   deg       = (int*)  alloc((size_t)N * 4);
  int*   offsets   = (int*)  alloc((size_t)(N + 1) * 4);
  int*   rank      = (int*)  alloc((size_t)E * 4);
  uint4* we        = (uint4*)alloc((size_t)E * 16);
  uint4* csr       = (uint4*)alloc((size_t)E * 32);
  float* Wz        = (float*)alloc(128 * 128 * 4);
  float* Ws        = (float*)alloc(128 * 4 * 4);
  float* Wd        = (float*)alloc(128 * 4 * 4);
  float* M         = (float*)alloc(32 * 4 * 4);
  float* cproj     = (float*)alloc(32 * 4);

  hipMemsetAsync(deg, 0, (size_t)N * 4, stream);

  k0_setup<<<69, 256, 0, stream>>>(W, proj_W, att_src, att_dst, lin_edge_W, att_edge,
                                   bias, proj_b, Wz, Ws, Wd, M, cproj);
  k3_gemm<<<512, 256, 0, stream>>>(x, Wz, Ws, Wd, N, Zp, a_src, a_dst);
  k1_edge<<<(E + 255) / 256, 256, 0, stream>>>(ei, E, (const float4*)ea, M,
                                               a_src, a_dst, we, deg, rank);
  k2_scan<<<1, 1024, 0, stream>>>(deg, N, offsets);
  k4_scatter<<<(E + 255) / 256, 256, 0, stream>>>(ei, E, rank, offsets, we, csr);
  k5_agg<<<2048, 256, 0, stream>>>(offsets, csr, Zp, a_src, a_dst, cproj, N, out);
}